// Round 1
// baseline (243.695 us; speedup 1.0000x reference)
//
#include <hip/hip_runtime.h>

#define Bb 16
#define Tt 12
#define Nn 1024
#define FIN 32
#define FOUT 64
#define KC 3
#define KJ (KC * Nn)     // 3072 — GEMM K dimension (k,j)
#define NO (Tt * FOUT)   // 768  — GEMM N dimension (t,o)

#define BM 128
#define BN 128
#define BK 64

typedef __attribute__((ext_vector_type(8))) short short8;
typedef __attribute__((ext_vector_type(4))) float f32x4;

__device__ __forceinline__ unsigned short f2bf(float f) {
  union { float f; unsigned u; } v; v.f = f;
  unsigned r = v.u + 0x7FFFu + ((v.u >> 16) & 1u);  // RNE
  return (unsigned short)(r >> 16);
}

// ---------------------------------------------------------------------------
// k1: A[b][i][k*N+j] = bf16(cheb[k,i,j] * att[b,i,j])
// ---------------------------------------------------------------------------
__global__ __launch_bounds__(256) void k1_build_A(
    const float* __restrict__ att, const float* __restrict__ cheb,
    unsigned short* __restrict__ Acat) {
  unsigned idx = blockIdx.x * 256u + threadIdx.x;  // (b, i, j/4)
  const int j = (idx & 255u) << 2;
  const int i = (idx >> 8) & 1023u;
  const int b = idx >> 18;
  const float4 av = *(const float4*)(att + ((size_t)b * Nn + i) * Nn + j);
  const size_t obase = ((size_t)b * Nn + i) * KJ + j;
#pragma unroll
  for (int k = 0; k < KC; ++k) {
    const float4 cv = *(const float4*)(cheb + ((size_t)k * Nn + i) * Nn + j);
    ushort4 o;
    o.x = f2bf(av.x * cv.x); o.y = f2bf(av.y * cv.y);
    o.z = f2bf(av.z * cv.z); o.w = f2bf(av.w * cv.w);
    *(ushort4*)(Acat + obase + (size_t)k * Nn) = o;
  }
}

// ---------------------------------------------------------------------------
// k2: Y[b][t*64+o][k*N+j] = bf16( sum_f x[b,t,j,f] * Theta[k,f,o] )
// each thread owns 2 consecutive j, writes packed bf16x2 (coalesced along j)
// ---------------------------------------------------------------------------
__global__ __launch_bounds__(256) void k2_build_Y(
    const float* __restrict__ x, const float* __restrict__ theta,
    unsigned short* __restrict__ Yw) {
  __shared__ float th[KC * FOUT * FIN];  // [k][o][f]
  const int tid = threadIdx.x;
  for (int s = tid; s < KC * FOUT * FIN; s += 256) {
    const int k = s >> 11, rem = s & 2047, o = rem >> 5, f = rem & 31;
    th[s] = theta[(k * FIN + f) * FOUT + o];
  }
  __syncthreads();
  const int blk = blockIdx.x;
  const int half = blk & 1, bt = blk >> 1;
  const int t = bt % Tt, b = bt / Tt;
  const int j0 = half * 512 + tid * 2;
  const float* xp = x + ((size_t)(b * Tt + t) * Nn + j0) * FIN;
  float x0[FIN], x1[FIN];
#pragma unroll
  for (int q = 0; q < FIN / 4; ++q) {
    float4 v = *(const float4*)(xp + 4 * q);
    x0[4 * q] = v.x; x0[4 * q + 1] = v.y; x0[4 * q + 2] = v.z; x0[4 * q + 3] = v.w;
    float4 u = *(const float4*)(xp + FIN + 4 * q);
    x1[4 * q] = u.x; x1[4 * q + 1] = u.y; x1[4 * q + 2] = u.z; x1[4 * q + 3] = u.w;
  }
  const size_t ybase = (size_t)(b * NO + t * FOUT) * KJ;
  for (int k = 0; k < KC; ++k) {
    for (int o = 0; o < FOUT; ++o) {
      const float* tp = &th[(k * FOUT + o) * FIN];
      float a0 = 0.f, a1 = 0.f;
#pragma unroll
      for (int q = 0; q < FIN / 4; ++q) {
        float4 tv = *(const float4*)(tp + 4 * q);
        a0 = fmaf(x0[4 * q + 0], tv.x, a0); a1 = fmaf(x1[4 * q + 0], tv.x, a1);
        a0 = fmaf(x0[4 * q + 1], tv.y, a0); a1 = fmaf(x1[4 * q + 1], tv.y, a1);
        a0 = fmaf(x0[4 * q + 2], tv.z, a0); a1 = fmaf(x1[4 * q + 2], tv.z, a1);
        a0 = fmaf(x0[4 * q + 3], tv.w, a0); a1 = fmaf(x1[4 * q + 3], tv.w, a1);
      }
      const unsigned pack = (unsigned)f2bf(a0) | ((unsigned)f2bf(a1) << 16);
      *(unsigned*)(Yw + ybase + (size_t)o * KJ + k * Nn + j0) = pack;
    }
  }
}

// ---------------------------------------------------------------------------
// k3: per b: C[i, n] = sum_kj A[i,kj] * Y[n,kj], ReLU, scatter to out[b,t,i,o]
// m97 structure: 128x128 tile, BK=64, 4 waves (2x2), global_load_lds dwordx4
// ---------------------------------------------------------------------------
__global__ __launch_bounds__(256) void k3_gemm(
    const unsigned short* __restrict__ A, const unsigned short* __restrict__ Yw,
    float* __restrict__ out) {
  __shared__ unsigned short As[BM * BK];
  __shared__ unsigned short Bs[BN * BK];
  const int bid = blockIdx.x;
  const int swz = (bid & 7) * 96 + (bid >> 3);  // 768 blocks, bijective XCD chunking
  const int b = swz / 48;
  const int r = swz % 48;
  const int it = r / 6;
  const int nt = r % 6;
  const unsigned short* Ap = A + ((size_t)b * Nn + it * BM) * KJ;
  const unsigned short* Bp = Yw + ((size_t)b * NO + nt * BN) * KJ;
  const int tid = threadIdx.x;
  const int w = tid >> 6, l = tid & 63;
  const int wr = w >> 1, wc = w & 1;
  const int srow = l >> 3;      // row within 8-row staging group
  const int schunk = l & 7;     // 16B chunk within 128B row
  const int lrow = l & 15;
  const int lk0 = (l >> 4) * 8;

  f32x4 acc[4][4];
#pragma unroll
  for (int mi = 0; mi < 4; ++mi)
#pragma unroll
    for (int ni = 0; ni < 4; ++ni)
      acc[mi][ni] = (f32x4){0.f, 0.f, 0.f, 0.f};

  for (int kt = 0; kt < KJ / BK; ++kt) {
    const int kofs = kt * BK;
#pragma unroll
    for (int g = 0; g < 4; ++g) {
      const int row = w * 32 + g * 8 + srow;
      __builtin_amdgcn_global_load_lds(
          (const __attribute__((address_space(1))) void*)(Ap + (size_t)row * KJ + kofs + schunk * 8),
          (__attribute__((address_space(3))) void*)(As + (w * 32 + g * 8) * BK),
          16, 0, 0);
    }
#pragma unroll
    for (int g = 0; g < 4; ++g) {
      const int row = w * 32 + g * 8 + srow;
      __builtin_amdgcn_global_load_lds(
          (const __attribute__((address_space(1))) void*)(Bp + (size_t)row * KJ + kofs + schunk * 8),
          (__attribute__((address_space(3))) void*)(Bs + (w * 32 + g * 8) * BK),
          16, 0, 0);
    }
    asm volatile("s_waitcnt vmcnt(0)");
    __syncthreads();
#pragma unroll
    for (int ks = 0; ks < 2; ++ks) {
      short8 af[4], bfr[4];
      const int lk = lk0 + ks * 32;
#pragma unroll
      for (int mi = 0; mi < 4; ++mi)
        af[mi] = *(const short8*)&As[(wr * 64 + mi * 16 + lrow) * BK + lk];
#pragma unroll
      for (int ni = 0; ni < 4; ++ni)
        bfr[ni] = *(const short8*)&Bs[(wc * 64 + ni * 16 + lrow) * BK + lk];
#pragma unroll
      for (int mi = 0; mi < 4; ++mi)
#pragma unroll
        for (int ni = 0; ni < 4; ++ni)
          acc[mi][ni] = __builtin_amdgcn_mfma_f32_16x16x32_bf16(af[mi], bfr[ni], acc[mi][ni], 0, 0, 0);
    }
    __syncthreads();
  }

  const int rbase = it * BM + wr * 64;
  const int cbase = nt * BN + wc * 64;
#pragma unroll
  for (int mi = 0; mi < 4; ++mi) {
#pragma unroll
    for (int ni = 0; ni < 4; ++ni) {
      const int col = cbase + ni * 16 + lrow;   // n = t*64 + o
      const int t = col >> 6, o = col & 63;
      const int row0 = rbase + mi * 16 + ((l >> 4) << 2);
      float* op = out + ((size_t)(b * Tt + t) * Nn + row0) * FOUT + o;
      f32x4 v = acc[mi][ni];
#pragma unroll
      for (int q = 0; q < 4; ++q)
        op[(size_t)q * FOUT] = fmaxf(v[q], 0.f);
    }
  }
}

// ---------------------------------------------------------------------------
// fallback (ws too small): slow but correct, pure f32
// ---------------------------------------------------------------------------
__global__ __launch_bounds__(128) void k_fallback(
    const float* __restrict__ x, const float* __restrict__ att,
    const float* __restrict__ cheb, const float* __restrict__ theta,
    float* __restrict__ out) {
  const int blk = blockIdx.x;  // (b, t, i)
  const int i = blk & 1023;
  const int bt = blk >> 10;
  const int t = bt % Tt, b = bt / Tt;
  __shared__ float rhs[KC * FIN];
  const int tid = threadIdx.x;
  if (tid < KC * FIN) {
    const int k = tid >> 5, f = tid & 31;
    const float* ar = att + ((size_t)b * Nn + i) * Nn;
    const float* cr = cheb + ((size_t)k * Nn + i) * Nn;
    const float* xr = x + ((size_t)(b * Tt + t) * Nn) * FIN + f;
    float s = 0.f;
    for (int j = 0; j < Nn; ++j) s = fmaf(ar[j] * cr[j], xr[(size_t)j * FIN], s);
    rhs[tid] = s;
  }
  __syncthreads();
  if (tid < FOUT) {
    float a = 0.f;
#pragma unroll
    for (int kf = 0; kf < KC * FIN; ++kf) a = fmaf(rhs[kf], theta[kf * FOUT + tid], a);
    out[((size_t)(b * Tt + t) * Nn + i) * FOUT + tid] = fmaxf(a, 0.f);
  }
}

extern "C" void kernel_launch(void* const* d_in, const int* in_sizes, int n_in,
                              void* d_out, int out_size, void* d_ws, size_t ws_size,
                              hipStream_t stream) {
  const float* x     = (const float*)d_in[0];
  const float* att   = (const float*)d_in[1];
  const float* cheb  = (const float*)d_in[2];
  const float* theta = (const float*)d_in[3];
  float* out = (float*)d_out;

  const size_t needA = (size_t)Bb * Nn * KJ * sizeof(unsigned short);  // 96 MB
  const size_t needY = (size_t)Bb * NO * KJ * sizeof(unsigned short);  // 72 MB
  if (ws_size >= needA + needY) {
    unsigned short* Acat = (unsigned short*)d_ws;
    unsigned short* Yw   = (unsigned short*)((char*)d_ws + needA);
    hipLaunchKernelGGL(k1_build_A, dim3(Bb * Nn * (Nn / 4) / 256), dim3(256), 0, stream,
                       att, cheb, Acat);
    hipLaunchKernelGGL(k2_build_Y, dim3(Bb * Tt * 2), dim3(256), 0, stream,
                       x, theta, Yw);
    hipLaunchKernelGGL(k3_gemm, dim3(Bb * (Nn / BM) * (NO / BN)), dim3(256), 0, stream,
                       Acat, Yw, out);
  } else {
    hipLaunchKernelGGL(k_fallback, dim3(Bb * Tt * Nn), dim3(128), 0, stream,
                       x, att, cheb, theta, out);
  }
}